// Round 17
// baseline (238.818 us; speedup 1.0000x reference)
//
#include <hip/hip_runtime.h>
#include <cstddef>
#include <cstdint>

#define B_     2
#define FEA_   128
#define H_     480
#define W_     360
#define NH_    32
#define PT_    32
#define EMB_   3
#define NPTS_  120000
#define BN_EPS_ 1e-5f
#define HW_    (H_ * W_)
#define NPTS_TOT_ (B_ * NPTS_)          // 240000
#define NCOMBO_   (B_ * 1024 * 32)      // 65536 distinct (b,cell,gn) combos
#define CGROUPS_  (NCOMBO_ / 16)        // 4096 MFMA groups
#define GPW_      4                     // combo-groups per wave
#define CWAVES_   (CGROUPS_ / GPW_)     // 1024 waves -> 256 blocks
#define HSTRIDE_  40                    // hbuf row stride in shorts (80B)
#define REP_K1_   16                    // MEASUREMENT: k1 = row/16
#define REP_SC_   12                    // MEASUREMENT: cold-dest reps; sc = row/12
#define OFF_ELEMS_ ((size_t)NPTS_TOT_ * EMB_)          // 720,000 floats
#define SCR_BASE_  ((size_t)4 * 1024 * 1024)           // 16MB in floats
#define SCR_STRIDE_ ((size_t)10 * 1024 * 1024)         // 40MB in floats

typedef float fx4   __attribute__((ext_vector_type(4)));
typedef float f32x4 __attribute__((ext_vector_type(4)));
typedef short bf16x8 __attribute__((ext_vector_type(8)));

static __device__ __forceinline__ short f2bf(float f) {
    union { float f; unsigned u; } v; v.f = f;
    return (short)((v.u + 0x7FFFu + ((v.u >> 16) & 1u)) >> 16);
}

// ---------------------------------------------------------------------------
// Kernel 1: 1x1 conv on the 32x32 sub-block, REP_K1_ idempotent repeats
// (measurement; identical output every rep).
// ---------------------------------------------------------------------------
__global__ __launch_bounds__(256)
void conv_sub_gemm(const float* __restrict__ x, const float* __restrict__ conv_w,
                   const float* __restrict__ conv_b, float* __restrict__ fea_sub)
{
    __shared__ float As[FEA_][64];       // [k][px]
    __shared__ float Bs[FEA_][72];       // [k][ch], pad 72
    const int b   = blockIdx.z;
    const int m0  = blockIdx.y * 64;
    const int o0  = blockIdx.x * 64;
    const int tid = threadIdx.x;
    const int tx  = tid & 15;
    const int ty  = tid >> 4;
    const int h0  = m0 >> 5;
    const float* xb = x + (size_t)b * FEA_ * HW_;

    for (int rep = 0; rep < REP_K1_; ++rep) {
        asm volatile("" ::: "memory");
        #pragma unroll
        for (int it = 0; it < 8; ++it) {
            const int e   = tid + it * 256;
            const int pxq = e & 15;
            const int k   = e >> 4;
            const int px  = pxq * 4;
            const fx4 v = *(const fx4*)&xb[(size_t)k * HW_ + (h0 + (px >> 5)) * W_ + (px & 31)];
            *(fx4*)&As[k][px] = v;
        }
        #pragma unroll
        for (int it = 0; it < 8; ++it) {
            const int e  = tid + it * 256;
            const int ch = e & 63;
            const int kq = e >> 6;
            const fx4 v = *(const fx4*)&conv_w[(size_t)(o0 + ch) * FEA_ + kq * 4];
            Bs[4 * kq + 0][ch] = v.x;
            Bs[4 * kq + 1][ch] = v.y;
            Bs[4 * kq + 2][ch] = v.z;
            Bs[4 * kq + 3][ch] = v.w;
        }
        __syncthreads();

        float acc[4][4] = {};
        #pragma unroll 8
        for (int k = 0; k < FEA_; ++k) {
            const fx4 av = *(const fx4*)&As[k][ty * 4];
            const fx4 bv = *(const fx4*)&Bs[k][tx * 4];
            #pragma unroll
            for (int i = 0; i < 4; ++i)
                #pragma unroll
                for (int j = 0; j < 4; ++j)
                    acc[i][j] += av[i] * bv[j];
        }

        const fx4 cb = *(const fx4*)&conv_b[o0 + tx * 4];
        #pragma unroll
        for (int i = 0; i < 4; ++i) {
            const int m = m0 + ty * 4 + i;
            fx4 v;
            v.x = acc[i][0] + cb.x; v.y = acc[i][1] + cb.y;
            v.z = acc[i][2] + cb.z; v.w = acc[i][3] + cb.w;
            __builtin_nontemporal_store(v,
                (fx4*)&fea_sub[((size_t)b * 1024 + m) * 1024 + o0 + tx * 4]);
        }
        __syncthreads();                 // WAR protection for next rep's stage
    }
}

// ---------------------------------------------------------------------------
// Kernel 1.5: dense MLP over 65536 combos (linear input reads). ~3.4us.
// ---------------------------------------------------------------------------
__global__ __launch_bounds__(256)
void dense_mlp(const float* __restrict__ fea_sub,
               const float* __restrict__ w1, const float* __restrict__ b1,
               const float* __restrict__ bn_gamma, const float* __restrict__ bn_beta,
               const float* __restrict__ bn_mean, const float* __restrict__ bn_var,
               const float* __restrict__ w2, const float* __restrict__ b2,
               float* __restrict__ off_tab)
{
    __shared__ __align__(16) short hbuf[4][GPW_][16 * HSTRIDE_];
    const int tid   = threadIdx.x;
    const int wib   = tid >> 6;
    const int lane  = tid & 63;
    const int gwave = blockIdx.x * 4 + wib;          // < 1024
    const int col = lane & 15;
    const int kg  = lane >> 4;

    bf16x8 w1f0, w1f1, w2f;
    {
        const float* r0 = &w1[(col)      * PT_ + kg * 8];
        const float* r1 = &w1[(col + 16) * PT_ + kg * 8];
        #pragma unroll
        for (int e = 0; e < 8; ++e) { w1f0[e] = f2bf(r0[e]); w1f1[e] = f2bf(r1[e]); }
        #pragma unroll
        for (int e = 0; e < 8; ++e)
            w2f[e] = (col < EMB_) ? f2bf(w2[col * PT_ + kg * 8 + e]) : (short)0;
    }
    const float sc0 = bn_gamma[col]      * rsqrtf(bn_var[col]      + BN_EPS_);
    const float sh0 = (b1[col]      - bn_mean[col])      * sc0 + bn_beta[col];
    const float sc1 = bn_gamma[col + 16] * rsqrtf(bn_var[col + 16] + BN_EPS_);
    const float sh1 = (b1[col + 16] - bn_mean[col + 16]) * sc1 + bn_beta[col + 16];
    const float bias2 = (col < EMB_) ? b2[col] : 0.0f;
    const f32x4 zc = {0.f, 0.f, 0.f, 0.f};
    const f32x4 c2init = {bias2, bias2, bias2, bias2};

    #pragma unroll
    for (int g = 0; g < GPW_; ++g) {
        short* hb = &hbuf[wib][g][0];
        const int cb0 = (gwave * GPW_ + g) * 16;

        const float* src = &fea_sub[(size_t)(cb0 + col) * 32 + kg * 8];
        const fx4 lo = *(const fx4*)&src[0];
        const fx4 hi = *(const fx4*)&src[4];

        bf16x8 af;
        af[0] = f2bf(lo.x); af[1] = f2bf(lo.y); af[2] = f2bf(lo.z); af[3] = f2bf(lo.w);
        af[4] = f2bf(hi.x); af[5] = f2bf(hi.y); af[6] = f2bf(hi.z); af[7] = f2bf(hi.w);

        f32x4 d0 = __builtin_amdgcn_mfma_f32_16x16x32_bf16(af, w1f0, zc, 0, 0, 0);
        f32x4 d1 = __builtin_amdgcn_mfma_f32_16x16x32_bf16(af, w1f1, zc, 0, 0, 0);

        #pragma unroll
        for (int r = 0; r < 4; ++r) {
            const float h0 = fmaxf(d0[r] * sc0 + sh0, 0.0f);
            const float h1 = fmaxf(d1[r] * sc1 + sh1, 0.0f);
            const int hrow = kg * 4 + r;
            hb[hrow * HSTRIDE_ + col]      = f2bf(h0);
            hb[hrow * HSTRIDE_ + col + 16] = f2bf(h1);
        }
        const bf16x8 a2 = *(const bf16x8*)&hb[col * HSTRIDE_ + kg * 8];

        const f32x4 c2 = __builtin_amdgcn_mfma_f32_16x16x32_bf16(a2, w2f, c2init, 0, 0, 0);
        if (col < EMB_) {
            #pragma unroll
            for (int r = 0; r < 4; ++r)
                off_tab[(size_t)(cb0 + kg * 4 + r) * 4 + col] = c2[r];
        }
    }
}

// ---------------------------------------------------------------------------
// Kernel 2: scatter (R15 body: 8 thr/pt, cached full-line stores), REP_SC_
// repeats with ROTATING COLD DESTINATIONS: reps 0..REP-2 write to distinct
// d_ws scratch regions (cold first-touch each rep, like the real replay);
// final rep writes the real outputs. Deterministic, outputs bit-identical.
// ---------------------------------------------------------------------------
__global__ __launch_bounds__(256)
void scatter_outputs(const float* __restrict__ fea_sub, const float* __restrict__ off_tab,
                     const int* __restrict__ grid_ind,
                     float* __restrict__ out_off, float* __restrict__ out_fea,
                     float* __restrict__ scratch, int reps)
{
    const int t    = blockIdx.x * 256 + threadIdx.x;   // < 1,920,000 exactly
    const int pp   = t >> 3;
    const int part = t & 7;

    for (int r = 0; r < reps; ++r) {
        asm volatile("" ::: "memory");
        float* o_off;
        float* o_fea;
        if (r == reps - 1 || scratch == nullptr) {
            o_off = out_off; o_fea = out_fea;
        } else {
            o_off = scratch + (size_t)r * SCR_STRIDE_;
            o_fea = o_off + OFF_ELEMS_;
        }
        const int bb = (pp >= NPTS_) ? 1 : 0;
        const int gh = grid_ind[pp * 3 + 0];
        const int gw = grid_ind[pp * 3 + 1];
        const int gn = grid_ind[pp * 3 + 2];
        const int combo = ((bb << 10) + (gh << 5) + gw) * 32 + gn;   // < 65536

        const fx4 v = *(const fx4*)&fea_sub[(size_t)combo * 32 + part * 4];
        *(fx4*)&o_fea[(size_t)pp * PT_ + part * 4] = v;              // cached, full line

        if (part < EMB_)
            o_off[(size_t)pp * EMB_ + part] = off_tab[(size_t)combo * 4 + part];
    }
}

// ---------------------------------------------------------------------------
// Fallback (only if ws_size < 9MB).
// ---------------------------------------------------------------------------
__global__ __launch_bounds__(256)
void fused_fallback(const float* __restrict__ x, const int* __restrict__ grid_ind,
                    const float* __restrict__ conv_w, const float* __restrict__ conv_b,
                    const float* __restrict__ w1, const float* __restrict__ b1,
                    const float* __restrict__ bn_gamma, const float* __restrict__ bn_beta,
                    const float* __restrict__ bn_mean, const float* __restrict__ bn_var,
                    const float* __restrict__ w2, const float* __restrict__ b2,
                    float* __restrict__ out_off, float* __restrict__ out_fea)
{
    __shared__ __align__(16) float s_x[8][FEA_];
    __shared__ float s_f[8][PT_ + 1];
    __shared__ float s_h[8][PT_ + 1];
    const int tid = threadIdx.x;
    const int lp  = tid >> 5;
    const int t   = tid & 31;
    const int p   = blockIdx.x * 8 + lp;

    const int b  = (p >= NPTS_) ? 1 : 0;
    const int gh = grid_ind[p * 3 + 0];
    const int gw = grid_ind[p * 3 + 1];
    const int gn = grid_ind[p * 3 + 2];

    const float* xb = x + (size_t)b * FEA_ * HW_ + gh * W_ + gw;
    #pragma unroll
    for (int i = 0; i < 4; ++i)
        s_x[lp][t + 32 * i] = xb[(size_t)(t + 32 * i) * HW_];
    __syncthreads();

    const int row = gn * PT_ + t;
    const float4* wr = (const float4*)(conv_w + row * FEA_);
    const float4* xv = (const float4*)s_x[lp];
    float a = 0.0f;
    #pragma unroll
    for (int i = 0; i < FEA_ / 4; ++i) {
        float4 wv = wr[i], xw = xv[i];
        a += wv.x * xw.x + wv.y * xw.y + wv.z * xw.z + wv.w * xw.w;
    }
    a += conv_b[row];
    s_f[lp][t] = a;
    out_fea[(size_t)p * PT_ + t] = a;
    __syncthreads();

    float hv = b1[t];
    #pragma unroll
    for (int j = 0; j < PT_; ++j) hv += s_f[lp][j] * w1[t * PT_ + j];
    const float sc = bn_gamma[t] * rsqrtf(bn_var[t] + BN_EPS_);
    hv = (hv - bn_mean[t]) * sc + bn_beta[t];
    s_h[lp][t] = fmaxf(hv, 0.0f);
    __syncthreads();

    if (t < EMB_) {
        float o = b2[t];
        #pragma unroll
        for (int j = 0; j < PT_; ++j) o += s_h[lp][j] * w2[t * PT_ + j];
        out_off[(size_t)p * EMB_ + t] = o;
    }
}

extern "C" void kernel_launch(void* const* d_in, const int* in_sizes, int n_in,
                              void* d_out, int out_size, void* d_ws, size_t ws_size,
                              hipStream_t stream)
{
    const float* x      = (const float*)d_in[0];
    const int*   gi     = (const int*)d_in[1];
    const float* conv_w = (const float*)d_in[2];
    const float* conv_b = (const float*)d_in[3];
    const float* w1     = (const float*)d_in[4];
    const float* b1     = (const float*)d_in[5];
    const float* bng    = (const float*)d_in[6];
    const float* bnb    = (const float*)d_in[7];
    const float* bnm    = (const float*)d_in[8];
    const float* bnv    = (const float*)d_in[9];
    const float* w2     = (const float*)d_in[10];
    const float* b2     = (const float*)d_in[11];

    float* out_off = (float*)d_out;                                  // [B,N,3]
    float* out_fea = out_off + (size_t)B_ * NPTS_ * EMB_;            // [B,N,32]

    const size_t fea_bytes = (size_t)B_ * 1024 * 1024 * sizeof(float);   // 8 MB
    const size_t tab_bytes = (size_t)NCOMBO_ * 4 * sizeof(float);        // 1 MB
    const size_t scr_need  = (SCR_BASE_ + (size_t)(REP_SC_ - 1) * SCR_STRIDE_) * sizeof(float);
    if (ws_size >= fea_bytes + tab_bytes) {
        float* fea_sub = (float*)d_ws;
        float* off_tab = (float*)((char*)d_ws + fea_bytes);
        float* scratch = (ws_size >= scr_need + OFF_ELEMS_ * sizeof(float))
                         ? ((float*)d_ws + SCR_BASE_) : nullptr;
        const int reps = scratch ? REP_SC_ : 1;
        conv_sub_gemm<<<dim3(16, 16, 2), 256, 0, stream>>>(x, conv_w, conv_b, fea_sub);
        dense_mlp<<<dim3(CWAVES_ / 4), 256, 0, stream>>>(
            fea_sub, w1, b1, bng, bnb, bnm, bnv, w2, b2, off_tab);
        scatter_outputs<<<dim3(NPTS_TOT_ * 8 / 256), 256, 0, stream>>>(
            fea_sub, off_tab, gi, out_off, out_fea, scratch, reps);
    } else {
        fused_fallback<<<dim3(B_ * NPTS_ / 8), 256, 0, stream>>>(
            x, gi, conv_w, conv_b, w1, b1, bng, bnb, bnm, bnv, w2, b2, out_off, out_fea);
    }
}

// Round 18
// 32.343 us; speedup vs baseline: 7.3839x; 7.3839x over previous
//
#include <hip/hip_runtime.h>
#include <cstddef>
#include <cstdint>

#define B_     2
#define FEA_   128
#define H_     480
#define W_     360
#define NH_    32
#define PT_    32
#define EMB_   3
#define NPTS_  120000
#define BN_EPS_ 1e-5f
#define HW_    (H_ * W_)
#define NPTS_TOT_ (B_ * NPTS_)          // 240000
#define NCOMBO_   (B_ * 1024 * 32)      // 65536 distinct (b,cell,gn) combos
#define HSTRIDE_  40                    // hbuf row stride in shorts (80B)
#define CS_STRIDE_ 36                   // Cs row stride in floats (144B, 16B-aligned)

typedef float fx4   __attribute__((ext_vector_type(4)));
typedef float f32x4 __attribute__((ext_vector_type(4)));
typedef short bf16x8 __attribute__((ext_vector_type(8)));

static __device__ __forceinline__ short f2bf(float f) {
    union { float f; unsigned u; } v; v.f = f;
    return (short)((v.u + 0x7FFFu + ((v.u >> 16) & 1u)) >> 16);
}

// ---------------------------------------------------------------------------
// Kernel 1 (fused): 1x1 conv on the 32x32 sub-block + in-block MLP epilogue.
// Conv: 64px x 64ch tile, K split into two 64-deep phases -> LDS 34 KB
// -> 4 blocks/CU (was 2 at 69.6 KB; k1 was VALU/occupancy-bound at 19%).
// Epilogue: the tile holds 128 complete (cell,gn) combos (gn*32 aligns with
// the 64-ch tile); acc -> LDS overlay Cs -> dm's wave-MFMA MLP -> off_tab.
// Identical arithmetic to the old dense_mlp (same frags, f2bf, MFMA order).
// ---------------------------------------------------------------------------
__global__ __launch_bounds__(256, 4)
void conv_mlp_fused(const float* __restrict__ x, const float* __restrict__ conv_w,
                    const float* __restrict__ conv_b,
                    const float* __restrict__ w1, const float* __restrict__ b1,
                    const float* __restrict__ bn_gamma, const float* __restrict__ bn_beta,
                    const float* __restrict__ bn_mean, const float* __restrict__ bn_var,
                    const float* __restrict__ w2, const float* __restrict__ b2,
                    float* __restrict__ fea_sub, float* __restrict__ off_tab)
{
    // 34816B arena. Conv phase: As[64][64] @0 (16384B), Bs[64][72] @16384 (18432B).
    // Epilogue overlay (after barrier): Cs[128][36] @0 (18432B), hbuf @18432 (5120B).
    __shared__ __align__(16) char smem[34816];
    float (*As)[64] = (float (*)[64])smem;
    float (*Bs)[72] = (float (*)[72])(smem + 16384);
    float (*Cs)[CS_STRIDE_] = (float (*)[CS_STRIDE_])smem;
    short* hbuf = (short*)(smem + 18432);            // [4 waves][16*HSTRIDE_]

    const int b   = blockIdx.z;
    const int m0  = blockIdx.y * 64;     // pixel tile base
    const int bx  = blockIdx.x;          // o0 = bx*64; gn = 2*bx + gnl
    const int o0  = bx * 64;
    const int tid = threadIdx.x;
    const int tx  = tid & 15;
    const int ty  = tid >> 4;
    const int h0  = m0 >> 5;
    const float* xb = x + (size_t)b * FEA_ * HW_;

    float acc[4][4] = {};
    #pragma unroll
    for (int kp = 0; kp < 2; ++kp) {
        const int k0 = kp * 64;
        // A tile: 64 k x 16 px-quads
        #pragma unroll
        for (int it = 0; it < 4; ++it) {
            const int e   = tid + it * 256;
            const int pxq = e & 15;
            const int k   = e >> 4;              // 0..63
            const int px  = pxq * 4;
            *(fx4*)&As[k][px] =
                *(const fx4*)&xb[(size_t)(k0 + k) * HW_ + (h0 + (px >> 5)) * W_ + (px & 31)];
        }
        // B tile (transpose): 64 ch x 16 k-quads
        #pragma unroll
        for (int it = 0; it < 4; ++it) {
            const int e  = tid + it * 256;
            const int ch = e & 63;
            const int kq = e >> 6;               // 0..15
            const fx4 v = *(const fx4*)&conv_w[(size_t)(o0 + ch) * FEA_ + k0 + kq * 4];
            Bs[4 * kq + 0][ch] = v.x;
            Bs[4 * kq + 1][ch] = v.y;
            Bs[4 * kq + 2][ch] = v.z;
            Bs[4 * kq + 3][ch] = v.w;
        }
        __syncthreads();
        #pragma unroll 8
        for (int k = 0; k < 64; ++k) {
            const fx4 av = *(const fx4*)&As[k][ty * 4];
            const fx4 bv = *(const fx4*)&Bs[k][tx * 4];
            #pragma unroll
            for (int i = 0; i < 4; ++i)
                #pragma unroll
                for (int j = 0; j < 4; ++j)
                    acc[i][j] += av[i] * bv[j];
        }
        __syncthreads();                         // WAR: restage / overlay safe
    }

    // Finalize conv: NT store fea_sub (full wave-contiguous lines) + Cs overlay
    {
        const fx4 cb = *(const fx4*)&conv_b[o0 + tx * 4];
        #pragma unroll
        for (int i = 0; i < 4; ++i) {
            const int m = m0 + ty * 4 + i;
            fx4 v;
            v.x = acc[i][0] + cb.x; v.y = acc[i][1] + cb.y;
            v.z = acc[i][2] + cb.z; v.w = acc[i][3] + cb.w;
            __builtin_nontemporal_store(v,
                (fx4*)&fea_sub[((size_t)b * 1024 + m) * 1024 + o0 + tx * 4]);
            // Cs[cl][f]: cl = local_px*2 + gnl, f = feature 0..31 (16B-aligned fx4)
            const int lpx = ty * 4 + i;
            const int gnl = tx >> 3;             // tx*4 >= 32 ?
            const int f0  = (tx & 7) * 4;
            *(fx4*)&Cs[lpx * 2 + gnl][f0] = v;
        }
    }
    __syncthreads();

    // Epilogue MLP (dm's exact math). Wave wid: combos cl = wid*32 + g*16 + ...
    const int wid  = tid >> 6;
    const int lane = tid & 63;
    const int col  = lane & 15;
    const int kg   = lane >> 4;
    short* hb = hbuf + wid * (16 * HSTRIDE_);

    bf16x8 w1f0, w1f1, w2f;
    {
        const float* r0 = &w1[(col)      * PT_ + kg * 8];
        const float* r1 = &w1[(col + 16) * PT_ + kg * 8];
        #pragma unroll
        for (int e = 0; e < 8; ++e) { w1f0[e] = f2bf(r0[e]); w1f1[e] = f2bf(r1[e]); }
        #pragma unroll
        for (int e = 0; e < 8; ++e)
            w2f[e] = (col < EMB_) ? f2bf(w2[col * PT_ + kg * 8 + e]) : (short)0;
    }
    const float sc0 = bn_gamma[col]      * rsqrtf(bn_var[col]      + BN_EPS_);
    const float sh0 = (b1[col]      - bn_mean[col])      * sc0 + bn_beta[col];
    const float sc1 = bn_gamma[col + 16] * rsqrtf(bn_var[col + 16] + BN_EPS_);
    const float sh1 = (b1[col + 16] - bn_mean[col + 16]) * sc1 + bn_beta[col + 16];
    const float bias2 = (col < EMB_) ? b2[col] : 0.0f;
    const f32x4 zc = {0.f, 0.f, 0.f, 0.f};
    const f32x4 c2init = {bias2, bias2, bias2, bias2};

    #pragma unroll
    for (int g = 0; g < 2; ++g) {
        const int cl0 = wid * 32 + g * 16;

        const fx4 lo = *(const fx4*)&Cs[cl0 + col][kg * 8];
        const fx4 hi = *(const fx4*)&Cs[cl0 + col][kg * 8 + 4];
        bf16x8 af;
        af[0] = f2bf(lo.x); af[1] = f2bf(lo.y); af[2] = f2bf(lo.z); af[3] = f2bf(lo.w);
        af[4] = f2bf(hi.x); af[5] = f2bf(hi.y); af[6] = f2bf(hi.z); af[7] = f2bf(hi.w);

        f32x4 d0 = __builtin_amdgcn_mfma_f32_16x16x32_bf16(af, w1f0, zc, 0, 0, 0);
        f32x4 d1 = __builtin_amdgcn_mfma_f32_16x16x32_bf16(af, w1f1, zc, 0, 0, 0);

        #pragma unroll
        for (int r = 0; r < 4; ++r) {
            const float h0v = fmaxf(d0[r] * sc0 + sh0, 0.0f);
            const float h1v = fmaxf(d1[r] * sc1 + sh1, 0.0f);
            const int hrow = kg * 4 + r;
            hb[hrow * HSTRIDE_ + col]      = f2bf(h0v);
            hb[hrow * HSTRIDE_ + col + 16] = f2bf(h1v);
        }
        const bf16x8 a2 = *(const bf16x8*)&hb[col * HSTRIDE_ + kg * 8];

        const f32x4 c2 = __builtin_amdgcn_mfma_f32_16x16x32_bf16(a2, w2f, c2init, 0, 0, 0);
        if (col < EMB_) {
            #pragma unroll
            for (int r = 0; r < 4; ++r) {
                const int cl  = cl0 + kg * 4 + r;
                const int m   = cl >> 1;
                const int gnl = cl & 1;
                const size_t combo = ((size_t)(b << 10) + (m0 + m)) * 32 + (bx * 2 + gnl);
                off_tab[combo * 4 + col] = c2[r];
            }
        }
    }
}

// ---------------------------------------------------------------------------
// Kernel 2: scatter (R15 winner): 8 threads/point, cached full-line stores.
// ---------------------------------------------------------------------------
__global__ __launch_bounds__(256)
void scatter_outputs(const float* __restrict__ fea_sub, const float* __restrict__ off_tab,
                     const int* __restrict__ grid_ind,
                     float* __restrict__ out_off, float* __restrict__ out_fea)
{
    const int t    = blockIdx.x * 256 + threadIdx.x;   // < 1,920,000 exactly
    const int pp   = t >> 3;
    const int part = t & 7;
    const int bb = (pp >= NPTS_) ? 1 : 0;
    const int gh = grid_ind[pp * 3 + 0];
    const int gw = grid_ind[pp * 3 + 1];
    const int gn = grid_ind[pp * 3 + 2];
    const int combo = ((bb << 10) + (gh << 5) + gw) * 32 + gn;   // < 65536

    const fx4 v = *(const fx4*)&fea_sub[(size_t)combo * 32 + part * 4];
    *(fx4*)&out_fea[(size_t)pp * PT_ + part * 4] = v;            // cached, full lines

    if (part < EMB_)
        out_off[(size_t)pp * EMB_ + part] = off_tab[(size_t)combo * 4 + part];
}

// ---------------------------------------------------------------------------
// Fallback (only if ws_size < 9MB).
// ---------------------------------------------------------------------------
__global__ __launch_bounds__(256)
void fused_fallback(const float* __restrict__ x, const int* __restrict__ grid_ind,
                    const float* __restrict__ conv_w, const float* __restrict__ conv_b,
                    const float* __restrict__ w1, const float* __restrict__ b1,
                    const float* __restrict__ bn_gamma, const float* __restrict__ bn_beta,
                    const float* __restrict__ bn_mean, const float* __restrict__ bn_var,
                    const float* __restrict__ w2, const float* __restrict__ b2,
                    float* __restrict__ out_off, float* __restrict__ out_fea)
{
    __shared__ __align__(16) float s_x[8][FEA_];
    __shared__ float s_f[8][PT_ + 1];
    __shared__ float s_h[8][PT_ + 1];
    const int tid = threadIdx.x;
    const int lp  = tid >> 5;
    const int t   = tid & 31;
    const int p   = blockIdx.x * 8 + lp;

    const int b  = (p >= NPTS_) ? 1 : 0;
    const int gh = grid_ind[p * 3 + 0];
    const int gw = grid_ind[p * 3 + 1];
    const int gn = grid_ind[p * 3 + 2];

    const float* xb = x + (size_t)b * FEA_ * HW_ + gh * W_ + gw;
    #pragma unroll
    for (int i = 0; i < 4; ++i)
        s_x[lp][t + 32 * i] = xb[(size_t)(t + 32 * i) * HW_];
    __syncthreads();

    const int row = gn * PT_ + t;
    const float4* wr = (const float4*)(conv_w + row * FEA_);
    const float4* xv = (const float4*)s_x[lp];
    float a = 0.0f;
    #pragma unroll
    for (int i = 0; i < FEA_ / 4; ++i) {
        float4 wv = wr[i], xw = xv[i];
        a += wv.x * xw.x + wv.y * xw.y + wv.z * xw.z + wv.w * xw.w;
    }
    a += conv_b[row];
    s_f[lp][t] = a;
    out_fea[(size_t)p * PT_ + t] = a;
    __syncthreads();

    float hv = b1[t];
    #pragma unroll
    for (int j = 0; j < PT_; ++j) hv += s_f[lp][j] * w1[t * PT_ + j];
    const float sc = bn_gamma[t] * rsqrtf(bn_var[t] + BN_EPS_);
    hv = (hv - bn_mean[t]) * sc + bn_beta[t];
    s_h[lp][t] = fmaxf(hv, 0.0f);
    __syncthreads();

    if (t < EMB_) {
        float o = b2[t];
        #pragma unroll
        for (int j = 0; j < PT_; ++j) o += s_h[lp][j] * w2[t * PT_ + j];
        out_off[(size_t)p * EMB_ + t] = o;
    }
}

extern "C" void kernel_launch(void* const* d_in, const int* in_sizes, int n_in,
                              void* d_out, int out_size, void* d_ws, size_t ws_size,
                              hipStream_t stream)
{
    const float* x      = (const float*)d_in[0];
    const int*   gi     = (const int*)d_in[1];
    const float* conv_w = (const float*)d_in[2];
    const float* conv_b = (const float*)d_in[3];
    const float* w1     = (const float*)d_in[4];
    const float* b1     = (const float*)d_in[5];
    const float* bng    = (const float*)d_in[6];
    const float* bnb    = (const float*)d_in[7];
    const float* bnm    = (const float*)d_in[8];
    const float* bnv    = (const float*)d_in[9];
    const float* w2     = (const float*)d_in[10];
    const float* b2     = (const float*)d_in[11];

    float* out_off = (float*)d_out;                                  // [B,N,3]
    float* out_fea = out_off + (size_t)B_ * NPTS_ * EMB_;            // [B,N,32]

    const size_t fea_bytes = (size_t)B_ * 1024 * 1024 * sizeof(float);   // 8 MB
    const size_t tab_bytes = (size_t)NCOMBO_ * 4 * sizeof(float);        // 1 MB
    if (ws_size >= fea_bytes + tab_bytes) {
        float* fea_sub = (float*)d_ws;
        float* off_tab = (float*)((char*)d_ws + fea_bytes);
        conv_mlp_fused<<<dim3(16, 16, 2), 256, 0, stream>>>(
            x, conv_w, conv_b, w1, b1, bng, bnb, bnm, bnv, w2, b2, fea_sub, off_tab);
        scatter_outputs<<<dim3(NPTS_TOT_ * 8 / 256), 256, 0, stream>>>(
            fea_sub, off_tab, gi, out_off, out_fea);
    } else {
        fused_fallback<<<dim3(B_ * NPTS_ / 8), 256, 0, stream>>>(
            x, gi, conv_w, conv_b, w1, b1, bng, bnb, bnm, bnv, w2, b2, out_off, out_fea);
    }
}